// Round 9
// baseline (1486.447 us; speedup 1.0000x reference)
//
#include <hip/hip_runtime.h>

// HamGraphConvolution: N=100k nodes, D=64 feats, H=4 heads (DK=16), E=1.6M edges.
// xt = c1*x + c2*(x@W^T)  (Hamiltonian 4-step linear recurrence folded on host)
// GAT-style attention normalized over col, aggregated over row.
// Softmax max-subtraction skipped: shift-invariant, eps 1e-16 unreachable.
// R9: k_node epilogue FORCE-unrolled (break -> per-j guard). R8 evidence:
//     full-unrolled main loop made the compiler skip epilogue unrolling;
//     runtime-indexed xi[]/p[] demoted to scratch -> 2.29 GB spill traffic
//     (FETCH 770MB/WRITE 1.46GB, VALU 1.8%, VGPR 64). All indices must be
//     compile-time for the arrays to scalarize. Main loop stays fully
//     unrolled (R7: runtime shfl idx = ds_bpermute on LDS pipe, 92us).

#define LRELU(v) ((v) > 0.0f ? (v) : 0.2f * (v))

#define EC 4096      // edges per hist/scatter block
#define BSC 256      // col-bucket size (shift 8)
#define BSR 128      // row-bucket size (shift 7)
#define NPW 8        // nodes per wave in k_node (reg-pressure bounded)

__global__ __launch_bounds__(256, 4) void k_node(const float* __restrict__ x,
                                                 const float* __restrict__ W,
                                                 const float* __restrict__ a,
                                                 float* __restrict__ xt,
                                                 float* __restrict__ s_src,
                                                 float* __restrict__ s_dst,
                                                 int n, float c1, float c2) {
    __shared__ float Ws[64 * 68];  // pad 68: float4-aligned; 2-way max (free)
    for (int i = threadIdx.x; i < 64 * 64; i += 256)
        Ws[(i >> 6) * 68 + (i & 63)] = W[i];
    __syncthreads();
    int wave = threadIdx.x >> 6;
    int lane = threadIdx.x & 63;
    float a_s = a[lane & 15];
    float a_d = a[16 + (lane & 15)];
    int nbase = (blockIdx.x * 4 + wave) * NPW;

    float xi[NPW];
#pragma unroll
    for (int j = 0; j < NPW; ++j) {
        int node = nbase + j;
        xi[j] = (node < n) ? x[(size_t)node * 64 + lane] : 0.0f;
    }
    float p[NPW];
#pragma unroll
    for (int j = 0; j < NPW; ++j) p[j] = 0.0f;

#pragma unroll
    for (int k4 = 0; k4 < 64; k4 += 4) {  // full unroll: shfl idx compile-time
        float4 wr = *(const float4*)(Ws + lane * 68 + k4);
#pragma unroll
        for (int j = 0; j < NPW; ++j) {
            p[j] = fmaf(__shfl(xi[j], k4 + 0, 64), wr.x, p[j]);
            p[j] = fmaf(__shfl(xi[j], k4 + 1, 64), wr.y, p[j]);
            p[j] = fmaf(__shfl(xi[j], k4 + 2, 64), wr.z, p[j]);
            p[j] = fmaf(__shfl(xi[j], k4 + 3, 64), wr.w, p[j]);
        }
    }

#pragma unroll
    for (int j = 0; j < NPW; ++j) {  // FORCED unroll: xi[j]/p[j] compile-time
        int node = nbase + j;        // -> arrays scalarize, no scratch
        if (node < n) {
            float xtv = c1 * xi[j] + c2 * p[j];
            xt[(size_t)node * 64 + lane] = xtv;
            float ss = xtv * a_s;
            float sd = xtv * a_d;
#pragma unroll
            for (int off = 8; off >= 1; off >>= 1) {
                ss += __shfl_xor(ss, off, 64);
                sd += __shfl_xor(sd, off, 64);
            }
            if ((lane & 15) == 0) {
                int h = lane >> 4;
                s_src[node * 4 + h] = ss;
                s_dst[node * 4 + h] = sd;
            }
        }
    }
}

// per-block LDS histograms of row>>7 and col>>8; H layout [bucket][block]
__global__ __launch_bounds__(256) void k_hist(const int* __restrict__ row,
                                              const int* __restrict__ col,
                                              int* __restrict__ Hr,
                                              int* __restrict__ Hc,
                                              int e, int nblk, int nbr, int nbc) {
    __shared__ int hr[1024];
    __shared__ int hc[512];
    int t = threadIdx.x;
    for (int i = t; i < 1024; i += 256) hr[i] = 0;
    for (int i = t; i < 512; i += 256) hc[i] = 0;
    __syncthreads();
    int base = blockIdx.x * EC;
#pragma unroll
    for (int j = 0; j < EC / 256; ++j) {
        int i = base + t + j * 256;
        if (i < e) {
            atomicAdd(&hr[row[i] >> 7], 1);
            atomicAdd(&hc[col[i] >> 8], 1);
        }
    }
    __syncthreads();
    for (int b = t; b < nbr; b += 256) Hr[(size_t)b * nblk + blockIdx.x] = hr[b];
    for (int b = t; b < nbc; b += 256) Hc[(size_t)b * nblk + blockIdx.x] = hc[b];
}

// exclusive scan of H[bucket][0..nblk) in place; Btot[bucket] = total. nblk<=512.
__global__ __launch_bounds__(256) void k_scanH(int* __restrict__ H,
                                               int* __restrict__ Btot, int nblk) {
    __shared__ int vals[512];
    __shared__ int part[256];
    int t = threadIdx.x;
    int* Hb = H + (size_t)blockIdx.x * nblk;
    for (int i = t; i < nblk; i += 256) vals[i] = Hb[i];
    __syncthreads();
    int c0 = t * 2;
    int s = 0;
#pragma unroll
    for (int j = 0; j < 2; ++j)
        if (c0 + j < nblk) s += vals[c0 + j];
    part[t] = s;
    __syncthreads();
    for (int d = 1; d < 256; d <<= 1) {
        int add = (t >= d) ? part[t - d] : 0;
        __syncthreads();
        part[t] += add;
        __syncthreads();
    }
    int run = part[t] - s;
#pragma unroll
    for (int j = 0; j < 2; ++j) {
        int i = c0 + j;
        if (i < nblk) {
            int v = vals[i];
            Hb[i] = run;
            run += v;
        }
    }
    if (t == 255) Btot[blockIdx.x] = part[255];
}

// exclusive scan of Btot[nb] -> Bbase[nb+1]
__global__ __launch_bounds__(256) void k_base(const int* __restrict__ Btot,
                                              int* __restrict__ Bbase, int nb) {
    __shared__ int part[256];
    __shared__ int carry;
    int t = threadIdx.x;
    if (t == 0) carry = 0;
    __syncthreads();
    for (int base = 0; base < nb; base += 256) {
        int i = base + t;
        int v = (i < nb) ? Btot[i] : 0;
        part[t] = v;
        __syncthreads();
        for (int d = 1; d < 256; d <<= 1) {
            int add = (t >= d) ? part[t - d] : 0;
            __syncthreads();
            part[t] += add;
            __syncthreads();
        }
        if (i < nb) Bbase[i] = carry + part[t] - v;
        __syncthreads();
        if (t == 0) carry += part[255];
        __syncthreads();
    }
    if (t == 0) Bbase[nb] = carry;
}

// scatter edges into c-bucketed ebc (payload r<<8|c_low) and r-bucketed ebr
// (payload c<<7|r_low) using LDS cursors; plain stores, no global atomics
__global__ __launch_bounds__(256) void k_scatter_dual(
    const int* __restrict__ row, const int* __restrict__ col,
    const int* __restrict__ Hr, const int* __restrict__ Hc,
    const int* __restrict__ BbR, const int* __restrict__ BbC,
    int* __restrict__ ebr, int* __restrict__ ebc,
    int e, int nblk, int nbr, int nbc) {
    __shared__ int curr[1024];
    __shared__ int curc[512];
    int t = threadIdx.x;
    int blk = blockIdx.x;
    for (int b = t; b < nbr; b += 256) curr[b] = BbR[b] + Hr[(size_t)b * nblk + blk];
    for (int b = t; b < nbc; b += 256) curc[b] = BbC[b] + Hc[(size_t)b * nblk + blk];
    __syncthreads();
    int base = blk * EC;
#pragma unroll
    for (int j = 0; j < EC / 256; ++j) {
        int i = base + t + j * 256;
        if (i < e) {
            int r = row[i], c = col[i];
            int pr = atomicAdd(&curr[r >> 7], 1);
            ebr[pr] = (c << 7) | (r & 127);
            int pc = atomicAdd(&curc[c >> 8], 1);
            ebc[pc] = (r << 8) | (c & 255);
        }
    }
}

// block per col-bucket: exp sums into LDS, write rden (no global atomics)
__global__ __launch_bounds__(256) void k_denom_b(const int* __restrict__ ebc,
                                                 const int* __restrict__ BbC,
                                                 const float* __restrict__ s_src,
                                                 const float* __restrict__ s_dst,
                                                 float* __restrict__ rden, int n) {
    __shared__ float acc[BSC * 4];
    __shared__ float sd[BSC * 4];
    int t = threadIdx.x;
    int b = blockIdx.x;
    int cbase = b << 8;
    for (int i = t; i < BSC * 4; i += 256) {
        acc[i] = 0.0f;
        int c4 = cbase * 4 + i;
        sd[i] = (c4 < n * 4) ? s_dst[c4] : 0.0f;
    }
    __syncthreads();
    int start = BbC[b], end = BbC[b + 1];
    for (int i = start + t; i < end; i += 256) {
        int p = ebc[i];
        int r = p >> 8, cl = p & 255;
        float4 ss = *(const float4*)(s_src + (size_t)r * 4);
        atomicAdd(&acc[cl * 4 + 0], __expf(LRELU(ss.x + sd[cl * 4 + 0])));
        atomicAdd(&acc[cl * 4 + 1], __expf(LRELU(ss.y + sd[cl * 4 + 1])));
        atomicAdd(&acc[cl * 4 + 2], __expf(LRELU(ss.z + sd[cl * 4 + 2])));
        atomicAdd(&acc[cl * 4 + 3], __expf(LRELU(ss.w + sd[cl * 4 + 3])));
    }
    __syncthreads();
    for (int i = t; i < BSC * 4; i += 256) {
        int c4 = cbase * 4 + i;
        if (c4 < n * 4) rden[c4] = 1.0f / (acc[i] + 1e-16f);
    }
}

// level-2 counting sort within row-bucket: ebr -> row-sorted (cw_c, cw_w),
// writes global rowptr; w computed here (thread-per-edge, independent loads)
__global__ __launch_bounds__(256) void k_sort2(const int* __restrict__ ebr,
                                               const int* __restrict__ BbR,
                                               const float* __restrict__ s_src,
                                               const float* __restrict__ s_dst,
                                               const float* __restrict__ rden,
                                               int* __restrict__ rowptr,
                                               int* __restrict__ cw_c,
                                               float* __restrict__ cw_w,
                                               int n, int e) {
    __shared__ int cnt[BSR];
    __shared__ int pfx[BSR];
    __shared__ int cur[BSR];
    __shared__ float ssh[BSR * 4];
    int t = threadIdx.x;
    int b = blockIdx.x;
    int rbase = b << 7;
    if (t < BSR) cnt[t] = 0;
    for (int i = t; i < BSR * 4; i += 256) {
        int g = rbase * 4 + i;
        ssh[i] = (g < n * 4) ? s_src[g] : 0.0f;
    }
    __syncthreads();
    int start = BbR[b], end = BbR[b + 1];
    for (int i = start + t; i < end; i += 256)
        atomicAdd(&cnt[ebr[i] & 127], 1);
    __syncthreads();
    if (t < BSR) pfx[t] = cnt[t];
    __syncthreads();
    for (int d = 1; d < BSR; d <<= 1) {
        int v = (t < BSR && t >= d) ? pfx[t - d] : 0;
        __syncthreads();
        if (t < BSR) pfx[t] += v;
        __syncthreads();
    }
    if (t < BSR) {
        int excl = start + pfx[t] - cnt[t];
        cur[t] = excl;
        int r = rbase + t;
        if (r < n) rowptr[r] = excl;
    }
    if (b == 0 && t == 0) rowptr[n] = e;
    __syncthreads();
    for (int i = start + t; i < end; i += 256) {
        int p = ebr[i];
        int rl = p & 127, c = p >> 7;
        float4 sd = *(const float4*)(s_dst + (size_t)c * 4);
        float4 rd = *(const float4*)(rden + (size_t)c * 4);
        float wv = __expf(LRELU(ssh[rl * 4 + 0] + sd.x)) * rd.x +
                   __expf(LRELU(ssh[rl * 4 + 1] + sd.y)) * rd.y +
                   __expf(LRELU(ssh[rl * 4 + 2] + sd.z)) * rd.z +
                   __expf(LRELU(ssh[rl * 4 + 3] + sd.w)) * rd.w;
        int pos = atomicAdd(&cur[rl], 1);
        cw_c[pos] = c;
        cw_w[pos] = 0.25f * wv;
    }
}

// wave-per-row CSR gather-reduce: register acc, 8 gathers in flight, no LDS
__global__ __launch_bounds__(256) void k_aggr(const int* __restrict__ rowptr,
                                              const int* __restrict__ cw_c,
                                              const float* __restrict__ cw_w,
                                              const float* __restrict__ xt,
                                              float* __restrict__ out, int n) {
    int r = blockIdx.x * 4 + (threadIdx.x >> 6);
    if (r >= n) return;
    int lane = threadIdx.x & 63;
    int start = rowptr[r], end = rowptr[r + 1];
    float acc = 0.0f;
    for (int base = start; base < end; base += 64) {
        int m = min(64, end - base);
        int cc = 0;
        float ww = 0.0f;
        if (lane < m) {
            cc = cw_c[base + lane];
            ww = cw_w[base + lane];
        }
        int k = 0;
        for (; k + 8 <= m; k += 8) {
            int c0 = __shfl(cc, k + 0, 64), c1 = __shfl(cc, k + 1, 64);
            int c2 = __shfl(cc, k + 2, 64), c3 = __shfl(cc, k + 3, 64);
            int c4 = __shfl(cc, k + 4, 64), c5 = __shfl(cc, k + 5, 64);
            int c6 = __shfl(cc, k + 6, 64), c7 = __shfl(cc, k + 7, 64);
            float w0 = __shfl(ww, k + 0, 64), w1 = __shfl(ww, k + 1, 64);
            float w2 = __shfl(ww, k + 2, 64), w3 = __shfl(ww, k + 3, 64);
            float w4 = __shfl(ww, k + 4, 64), w5 = __shfl(ww, k + 5, 64);
            float w6 = __shfl(ww, k + 6, 64), w7 = __shfl(ww, k + 7, 64);
            float x0 = xt[(size_t)c0 * 64 + lane];
            float x1 = xt[(size_t)c1 * 64 + lane];
            float x2 = xt[(size_t)c2 * 64 + lane];
            float x3 = xt[(size_t)c3 * 64 + lane];
            float x4 = xt[(size_t)c4 * 64 + lane];
            float x5 = xt[(size_t)c5 * 64 + lane];
            float x6 = xt[(size_t)c6 * 64 + lane];
            float x7 = xt[(size_t)c7 * 64 + lane];
            acc = fmaf(w0, x0, acc);
            acc = fmaf(w1, x1, acc);
            acc = fmaf(w2, x2, acc);
            acc = fmaf(w3, x3, acc);
            acc = fmaf(w4, x4, acc);
            acc = fmaf(w5, x5, acc);
            acc = fmaf(w6, x6, acc);
            acc = fmaf(w7, x7, acc);
        }
        for (; k < m; ++k) {
            int c0 = __shfl(cc, k, 64);
            float w0 = __shfl(ww, k, 64);
            acc = fmaf(w0, xt[(size_t)c0 * 64 + lane], acc);
        }
    }
    out[(size_t)r * 64 + lane] = acc;
}

extern "C" void kernel_launch(void* const* d_in, const int* in_sizes, int n_in,
                              void* d_out, int out_size, void* d_ws, size_t ws_size,
                              hipStream_t stream) {
    const float* x = (const float*)d_in[0];
    const int* ei = (const int*)d_in[1];
    // d_in[2] = edge_weight: unused by the reference
    const float* W = (const float*)d_in[3];
    const float* a = (const float*)d_in[4];
    int n = in_sizes[0] / 64;
    int e = in_sizes[1] / 2;
    const int* row = ei;
    const int* col = ei + e;
    float* out = (float*)d_out;

    int nblk = (e + EC - 1) / EC;       // 391 (<=512 for k_scanH)
    int nbr = (n + BSR - 1) / BSR;      // 782 (<=1024)
    int nbc = (n + BSC - 1) / BSC;      // 391 (<=512)

    size_t o = 0;
    auto take = [&](size_t cnt) {
        size_t p = o;
        o += (cnt + 3) & ~(size_t)3;
        return p;
    };
    int* wsi = (int*)d_ws;
    float* xt = (float*)(wsi + take((size_t)n * 64));
    float* s_src = (float*)(wsi + take((size_t)n * 4));
    float* s_dst = (float*)(wsi + take((size_t)n * 4));
    float* rden = (float*)(wsi + take((size_t)n * 4));
    int* Hr = wsi + take((size_t)nbr * nblk);
    int* Hc = wsi + take((size_t)nbc * nblk);
    int* BtotR = wsi + take(nbr);
    int* BbR = wsi + take(nbr + 1);
    int* BtotC = wsi + take(nbc);
    int* BbC = wsi + take(nbc + 1);
    int* ebr = wsi + take(e);
    int* ebc = wsi + take(e);
    float* cw_w = (float*)(wsi + take(e));
    int* rowptr = wsi + take(n + 1);
    int* cw_c = ebc;  // alias: ebc dead after k_denom_b, k_sort2 runs after

    // Fold 4-step (q,p) <- (q+0.25p, p-0.25q): xt = aq*x + bq*(x@W^T)
    float aq = 1.f, bq = 0.f, ap = 0.f, bp = 1.f;
    for (int i = 0; i < 4; ++i) {
        float naq = aq + 0.25f * ap, nbq = bq + 0.25f * bp;
        float nap = ap - 0.25f * aq, nbp = bp - 0.25f * bq;
        aq = naq; bq = nbq; ap = nap; bp = nbp;
    }

    int npb = 4 * NPW;  // nodes per block
    k_node<<<(n + npb - 1) / npb, 256, 0, stream>>>(x, W, a, xt, s_src, s_dst,
                                                    n, aq, bq);
    k_hist<<<nblk, 256, 0, stream>>>(row, col, Hr, Hc, e, nblk, nbr, nbc);
    k_scanH<<<nbr, 256, 0, stream>>>(Hr, BtotR, nblk);
    k_scanH<<<nbc, 256, 0, stream>>>(Hc, BtotC, nblk);
    k_base<<<1, 256, 0, stream>>>(BtotR, BbR, nbr);
    k_base<<<1, 256, 0, stream>>>(BtotC, BbC, nbc);
    k_scatter_dual<<<nblk, 256, 0, stream>>>(row, col, Hr, Hc, BbR, BbC,
                                             ebr, ebc, e, nblk, nbr, nbc);
    k_denom_b<<<nbc, 256, 0, stream>>>(ebc, BbC, s_src, s_dst, rden, n);
    k_sort2<<<nbr, 256, 0, stream>>>(ebr, BbR, s_src, s_dst, rden,
                                     rowptr, cw_c, cw_w, n, e);
    k_aggr<<<(n + 3) / 4, 256, 0, stream>>>(rowptr, cw_c, cw_w, xt, out, n);
}

// Round 10
// 343.911 us; speedup vs baseline: 4.3222x; 4.3222x over previous
//
#include <hip/hip_runtime.h>

// HamGraphConvolution: N=100k nodes, D=64 feats, H=4 heads (DK=16), E=1.6M edges.
// xt = c1*x + c2*(x@W^T)  (Hamiltonian 4-step linear recurrence folded on host)
// GAT-style attention normalized over col, aggregated over row.
// Softmax max-subtraction skipped: shift-invariant, eps 1e-16 unreachable.
// R10: k_node rewritten shfl-free. R8/R9 evidence: __shfl needs compile-time
//     lane -> full unroll -> 16 hoisted float4 + 512 temps -> allocator spills
//     arrays to scratch (2.3GB traffic) regardless of epilogue. New structure:
//     x-tile in LDS, wave-uniform ds_read_b128 broadcast per node (runtime
//     addresses legal -> loop stays rolled, live-set ~28 VGPR, no spike).

#define LRELU(v) ((v) > 0.0f ? (v) : 0.2f * (v))

#define EC 4096      // edges per hist/scatter block
#define BSC 256      // col-bucket size (shift 8)
#define BSR 128      // row-bucket size (shift 7)
#define NPW 8        // nodes per wave in k_node
#define NPB 32       // nodes per block (4 waves)

__global__ __launch_bounds__(256) void k_node(const float* __restrict__ x,
                                              const float* __restrict__ W,
                                              const float* __restrict__ a,
                                              float* __restrict__ xt,
                                              float* __restrict__ s_src,
                                              float* __restrict__ s_dst,
                                              int n, float c1, float c2) {
    __shared__ float Ws[64 * 68];   // pad 68: float4-aligned rows
    __shared__ float xs[NPB * 64];  // x-tile: 8 KB
    int t = threadIdx.x;
    for (int i = t; i < 64 * 64; i += 256)
        Ws[(i >> 6) * 68 + (i & 63)] = W[i];
    {
        size_t gbase = (size_t)blockIdx.x * NPB * 64;
        for (int i = t; i < NPB * 64; i += 256) {
            size_t g = gbase + i;
            xs[i] = (g < (size_t)n * 64) ? x[g] : 0.0f;  // coalesced
        }
    }
    __syncthreads();
    int wave = t >> 6;
    int lane = t & 63;
    float a_s = a[lane & 15];
    float a_d = a[16 + (lane & 15)];
    int nbase = blockIdx.x * NPB + wave * NPW;
    const float* xw = xs + wave * NPW * 64;

    float p[NPW];
#pragma unroll
    for (int j = 0; j < NPW; ++j) p[j] = 0.0f;

#pragma unroll 2
    for (int k4 = 0; k4 < 64; k4 += 4) {
        // per-lane W row segment (b128); x reads are wave-uniform -> broadcast
        float4 wr = *(const float4*)(Ws + lane * 68 + k4);
#pragma unroll
        for (int j = 0; j < NPW; ++j) {
            float4 xb = *(const float4*)(xw + j * 64 + k4);
            p[j] = fmaf(xb.x, wr.x, p[j]);
            p[j] = fmaf(xb.y, wr.y, p[j]);
            p[j] = fmaf(xb.z, wr.z, p[j]);
            p[j] = fmaf(xb.w, wr.w, p[j]);
        }
    }

#pragma unroll
    for (int j = 0; j < NPW; ++j) {  // constant j: p[] scalarizes
        int node = nbase + j;
        if (node < n) {
            float xv = xw[j * 64 + lane];  // per-lane, stride-1 (2-way, free)
            float xtv = c1 * xv + c2 * p[j];
            xt[(size_t)node * 64 + lane] = xtv;
            float ss = xtv * a_s;
            float sd = xtv * a_d;
#pragma unroll
            for (int off = 8; off >= 1; off >>= 1) {
                ss += __shfl_xor(ss, off, 64);
                sd += __shfl_xor(sd, off, 64);
            }
            if ((lane & 15) == 0) {
                int h = lane >> 4;
                s_src[node * 4 + h] = ss;
                s_dst[node * 4 + h] = sd;
            }
        }
    }
}

// per-block LDS histograms of row>>7 and col>>8; H layout [bucket][block]
__global__ __launch_bounds__(256) void k_hist(const int* __restrict__ row,
                                              const int* __restrict__ col,
                                              int* __restrict__ Hr,
                                              int* __restrict__ Hc,
                                              int e, int nblk, int nbr, int nbc) {
    __shared__ int hr[1024];
    __shared__ int hc[512];
    int t = threadIdx.x;
    for (int i = t; i < 1024; i += 256) hr[i] = 0;
    for (int i = t; i < 512; i += 256) hc[i] = 0;
    __syncthreads();
    int base = blockIdx.x * EC;
#pragma unroll
    for (int j = 0; j < EC / 256; ++j) {
        int i = base + t + j * 256;
        if (i < e) {
            atomicAdd(&hr[row[i] >> 7], 1);
            atomicAdd(&hc[col[i] >> 8], 1);
        }
    }
    __syncthreads();
    for (int b = t; b < nbr; b += 256) Hr[(size_t)b * nblk + blockIdx.x] = hr[b];
    for (int b = t; b < nbc; b += 256) Hc[(size_t)b * nblk + blockIdx.x] = hc[b];
}

// exclusive scan of H[bucket][0..nblk) in place; Btot[bucket] = total. nblk<=512.
__global__ __launch_bounds__(256) void k_scanH(int* __restrict__ H,
                                               int* __restrict__ Btot, int nblk) {
    __shared__ int vals[512];
    __shared__ int part[256];
    int t = threadIdx.x;
    int* Hb = H + (size_t)blockIdx.x * nblk;
    for (int i = t; i < nblk; i += 256) vals[i] = Hb[i];
    __syncthreads();
    int c0 = t * 2;
    int s = 0;
#pragma unroll
    for (int j = 0; j < 2; ++j)
        if (c0 + j < nblk) s += vals[c0 + j];
    part[t] = s;
    __syncthreads();
    for (int d = 1; d < 256; d <<= 1) {
        int add = (t >= d) ? part[t - d] : 0;
        __syncthreads();
        part[t] += add;
        __syncthreads();
    }
    int run = part[t] - s;
#pragma unroll
    for (int j = 0; j < 2; ++j) {
        int i = c0 + j;
        if (i < nblk) {
            int v = vals[i];
            Hb[i] = run;
            run += v;
        }
    }
    if (t == 255) Btot[blockIdx.x] = part[255];
}

// exclusive scan of Btot[nb] -> Bbase[nb+1]
__global__ __launch_bounds__(256) void k_base(const int* __restrict__ Btot,
                                              int* __restrict__ Bbase, int nb) {
    __shared__ int part[256];
    __shared__ int carry;
    int t = threadIdx.x;
    if (t == 0) carry = 0;
    __syncthreads();
    for (int base = 0; base < nb; base += 256) {
        int i = base + t;
        int v = (i < nb) ? Btot[i] : 0;
        part[t] = v;
        __syncthreads();
        for (int d = 1; d < 256; d <<= 1) {
            int add = (t >= d) ? part[t - d] : 0;
            __syncthreads();
            part[t] += add;
            __syncthreads();
        }
        if (i < nb) Bbase[i] = carry + part[t] - v;
        __syncthreads();
        if (t == 0) carry += part[255];
        __syncthreads();
    }
    if (t == 0) Bbase[nb] = carry;
}

// scatter edges into c-bucketed ebc (payload r<<8|c_low) and r-bucketed ebr
// (payload c<<7|r_low) using LDS cursors; plain stores, no global atomics
__global__ __launch_bounds__(256) void k_scatter_dual(
    const int* __restrict__ row, const int* __restrict__ col,
    const int* __restrict__ Hr, const int* __restrict__ Hc,
    const int* __restrict__ BbR, const int* __restrict__ BbC,
    int* __restrict__ ebr, int* __restrict__ ebc,
    int e, int nblk, int nbr, int nbc) {
    __shared__ int curr[1024];
    __shared__ int curc[512];
    int t = threadIdx.x;
    int blk = blockIdx.x;
    for (int b = t; b < nbr; b += 256) curr[b] = BbR[b] + Hr[(size_t)b * nblk + blk];
    for (int b = t; b < nbc; b += 256) curc[b] = BbC[b] + Hc[(size_t)b * nblk + blk];
    __syncthreads();
    int base = blk * EC;
#pragma unroll
    for (int j = 0; j < EC / 256; ++j) {
        int i = base + t + j * 256;
        if (i < e) {
            int r = row[i], c = col[i];
            int pr = atomicAdd(&curr[r >> 7], 1);
            ebr[pr] = (c << 7) | (r & 127);
            int pc = atomicAdd(&curc[c >> 8], 1);
            ebc[pc] = (r << 8) | (c & 255);
        }
    }
}

// block per col-bucket: exp sums into LDS, write rden (no global atomics)
__global__ __launch_bounds__(256) void k_denom_b(const int* __restrict__ ebc,
                                                 const int* __restrict__ BbC,
                                                 const float* __restrict__ s_src,
                                                 const float* __restrict__ s_dst,
                                                 float* __restrict__ rden, int n) {
    __shared__ float acc[BSC * 4];
    __shared__ float sd[BSC * 4];
    int t = threadIdx.x;
    int b = blockIdx.x;
    int cbase = b << 8;
    for (int i = t; i < BSC * 4; i += 256) {
        acc[i] = 0.0f;
        int c4 = cbase * 4 + i;
        sd[i] = (c4 < n * 4) ? s_dst[c4] : 0.0f;
    }
    __syncthreads();
    int start = BbC[b], end = BbC[b + 1];
    for (int i = start + t; i < end; i += 256) {
        int p = ebc[i];
        int r = p >> 8, cl = p & 255;
        float4 ss = *(const float4*)(s_src + (size_t)r * 4);
        atomicAdd(&acc[cl * 4 + 0], __expf(LRELU(ss.x + sd[cl * 4 + 0])));
        atomicAdd(&acc[cl * 4 + 1], __expf(LRELU(ss.y + sd[cl * 4 + 1])));
        atomicAdd(&acc[cl * 4 + 2], __expf(LRELU(ss.z + sd[cl * 4 + 2])));
        atomicAdd(&acc[cl * 4 + 3], __expf(LRELU(ss.w + sd[cl * 4 + 3])));
    }
    __syncthreads();
    for (int i = t; i < BSC * 4; i += 256) {
        int c4 = cbase * 4 + i;
        if (c4 < n * 4) rden[c4] = 1.0f / (acc[i] + 1e-16f);
    }
}

// level-2 counting sort within row-bucket: ebr -> row-sorted (cw_c, cw_w),
// writes global rowptr; w computed here (thread-per-edge, independent loads)
__global__ __launch_bounds__(256) void k_sort2(const int* __restrict__ ebr,
                                               const int* __restrict__ BbR,
                                               const float* __restrict__ s_src,
                                               const float* __restrict__ s_dst,
                                               const float* __restrict__ rden,
                                               int* __restrict__ rowptr,
                                               int* __restrict__ cw_c,
                                               float* __restrict__ cw_w,
                                               int n, int e) {
    __shared__ int cnt[BSR];
    __shared__ int pfx[BSR];
    __shared__ int cur[BSR];
    __shared__ float ssh[BSR * 4];
    int t = threadIdx.x;
    int b = blockIdx.x;
    int rbase = b << 7;
    if (t < BSR) cnt[t] = 0;
    for (int i = t; i < BSR * 4; i += 256) {
        int g = rbase * 4 + i;
        ssh[i] = (g < n * 4) ? s_src[g] : 0.0f;
    }
    __syncthreads();
    int start = BbR[b], end = BbR[b + 1];
    for (int i = start + t; i < end; i += 256)
        atomicAdd(&cnt[ebr[i] & 127], 1);
    __syncthreads();
    if (t < BSR) pfx[t] = cnt[t];
    __syncthreads();
    for (int d = 1; d < BSR; d <<= 1) {
        int v = (t < BSR && t >= d) ? pfx[t - d] : 0;
        __syncthreads();
        if (t < BSR) pfx[t] += v;
        __syncthreads();
    }
    if (t < BSR) {
        int excl = start + pfx[t] - cnt[t];
        cur[t] = excl;
        int r = rbase + t;
        if (r < n) rowptr[r] = excl;
    }
    if (b == 0 && t == 0) rowptr[n] = e;
    __syncthreads();
    for (int i = start + t; i < end; i += 256) {
        int p = ebr[i];
        int rl = p & 127, c = p >> 7;
        float4 sd = *(const float4*)(s_dst + (size_t)c * 4);
        float4 rd = *(const float4*)(rden + (size_t)c * 4);
        float wv = __expf(LRELU(ssh[rl * 4 + 0] + sd.x)) * rd.x +
                   __expf(LRELU(ssh[rl * 4 + 1] + sd.y)) * rd.y +
                   __expf(LRELU(ssh[rl * 4 + 2] + sd.z)) * rd.z +
                   __expf(LRELU(ssh[rl * 4 + 3] + sd.w)) * rd.w;
        int pos = atomicAdd(&cur[rl], 1);
        cw_c[pos] = c;
        cw_w[pos] = 0.25f * wv;
    }
}

// wave-per-row CSR gather-reduce: register acc, 8 gathers in flight, no LDS
__global__ __launch_bounds__(256) void k_aggr(const int* __restrict__ rowptr,
                                              const int* __restrict__ cw_c,
                                              const float* __restrict__ cw_w,
                                              const float* __restrict__ xt,
                                              float* __restrict__ out, int n) {
    int r = blockIdx.x * 4 + (threadIdx.x >> 6);
    if (r >= n) return;
    int lane = threadIdx.x & 63;
    int start = rowptr[r], end = rowptr[r + 1];
    float acc = 0.0f;
    for (int base = start; base < end; base += 64) {
        int m = min(64, end - base);
        int cc = 0;
        float ww = 0.0f;
        if (lane < m) {
            cc = cw_c[base + lane];
            ww = cw_w[base + lane];
        }
        int k = 0;
        for (; k + 8 <= m; k += 8) {
            int c0 = __shfl(cc, k + 0, 64), c1 = __shfl(cc, k + 1, 64);
            int c2 = __shfl(cc, k + 2, 64), c3 = __shfl(cc, k + 3, 64);
            int c4 = __shfl(cc, k + 4, 64), c5 = __shfl(cc, k + 5, 64);
            int c6 = __shfl(cc, k + 6, 64), c7 = __shfl(cc, k + 7, 64);
            float w0 = __shfl(ww, k + 0, 64), w1 = __shfl(ww, k + 1, 64);
            float w2 = __shfl(ww, k + 2, 64), w3 = __shfl(ww, k + 3, 64);
            float w4 = __shfl(ww, k + 4, 64), w5 = __shfl(ww, k + 5, 64);
            float w6 = __shfl(ww, k + 6, 64), w7 = __shfl(ww, k + 7, 64);
            float x0 = xt[(size_t)c0 * 64 + lane];
            float x1 = xt[(size_t)c1 * 64 + lane];
            float x2 = xt[(size_t)c2 * 64 + lane];
            float x3 = xt[(size_t)c3 * 64 + lane];
            float x4 = xt[(size_t)c4 * 64 + lane];
            float x5 = xt[(size_t)c5 * 64 + lane];
            float x6 = xt[(size_t)c6 * 64 + lane];
            float x7 = xt[(size_t)c7 * 64 + lane];
            acc = fmaf(w0, x0, acc);
            acc = fmaf(w1, x1, acc);
            acc = fmaf(w2, x2, acc);
            acc = fmaf(w3, x3, acc);
            acc = fmaf(w4, x4, acc);
            acc = fmaf(w5, x5, acc);
            acc = fmaf(w6, x6, acc);
            acc = fmaf(w7, x7, acc);
        }
        for (; k < m; ++k) {
            int c0 = __shfl(cc, k, 64);
            float w0 = __shfl(ww, k, 64);
            acc = fmaf(w0, xt[(size_t)c0 * 64 + lane], acc);
        }
    }
    out[(size_t)r * 64 + lane] = acc;
}

extern "C" void kernel_launch(void* const* d_in, const int* in_sizes, int n_in,
                              void* d_out, int out_size, void* d_ws, size_t ws_size,
                              hipStream_t stream) {
    const float* x = (const float*)d_in[0];
    const int* ei = (const int*)d_in[1];
    // d_in[2] = edge_weight: unused by the reference
    const float* W = (const float*)d_in[3];
    const float* a = (const float*)d_in[4];
    int n = in_sizes[0] / 64;
    int e = in_sizes[1] / 2;
    const int* row = ei;
    const int* col = ei + e;
    float* out = (float*)d_out;

    int nblk = (e + EC - 1) / EC;       // 391 (<=512 for k_scanH)
    int nbr = (n + BSR - 1) / BSR;      // 782 (<=1024)
    int nbc = (n + BSC - 1) / BSC;      // 391 (<=512)

    size_t o = 0;
    auto take = [&](size_t cnt) {
        size_t p = o;
        o += (cnt + 3) & ~(size_t)3;
        return p;
    };
    int* wsi = (int*)d_ws;
    float* xt = (float*)(wsi + take((size_t)n * 64));
    float* s_src = (float*)(wsi + take((size_t)n * 4));
    float* s_dst = (float*)(wsi + take((size_t)n * 4));
    float* rden = (float*)(wsi + take((size_t)n * 4));
    int* Hr = wsi + take((size_t)nbr * nblk);
    int* Hc = wsi + take((size_t)nbc * nblk);
    int* BtotR = wsi + take(nbr);
    int* BbR = wsi + take(nbr + 1);
    int* BtotC = wsi + take(nbc);
    int* BbC = wsi + take(nbc + 1);
    int* ebr = wsi + take(e);
    int* ebc = wsi + take(e);
    float* cw_w = (float*)(wsi + take(e));
    int* rowptr = wsi + take(n + 1);
    int* cw_c = ebc;  // alias: ebc dead after k_denom_b, k_sort2 runs after

    // Fold 4-step (q,p) <- (q+0.25p, p-0.25q): xt = aq*x + bq*(x@W^T)
    float aq = 1.f, bq = 0.f, ap = 0.f, bp = 1.f;
    for (int i = 0; i < 4; ++i) {
        float naq = aq + 0.25f * ap, nbq = bq + 0.25f * bp;
        float nap = ap - 0.25f * aq, nbp = bp - 0.25f * bq;
        aq = naq; bq = nbq; ap = nap; bp = nbp;
    }

    k_node<<<(n + NPB - 1) / NPB, 256, 0, stream>>>(x, W, a, xt, s_src, s_dst,
                                                    n, aq, bq);
    k_hist<<<nblk, 256, 0, stream>>>(row, col, Hr, Hc, e, nblk, nbr, nbc);
    k_scanH<<<nbr, 256, 0, stream>>>(Hr, BtotR, nblk);
    k_scanH<<<nbc, 256, 0, stream>>>(Hc, BtotC, nblk);
    k_base<<<1, 256, 0, stream>>>(BtotR, BbR, nbr);
    k_base<<<1, 256, 0, stream>>>(BtotC, BbC, nbc);
    k_scatter_dual<<<nblk, 256, 0, stream>>>(row, col, Hr, Hc, BbR, BbC,
                                             ebr, ebc, e, nblk, nbr, nbc);
    k_denom_b<<<nbc, 256, 0, stream>>>(ebc, BbC, s_src, s_dst, rden, n);
    k_sort2<<<nbr, 256, 0, stream>>>(ebr, BbR, s_src, s_dst, rden,
                                     rowptr, cw_c, cw_w, n, e);
    k_aggr<<<(n + 3) / 4, 256, 0, stream>>>(rowptr, cw_c, cw_w, xt, out, n);
}

// Round 11
// 327.721 us; speedup vs baseline: 4.5357x; 1.0494x over previous
//
#include <hip/hip_runtime.h>
#include <hip/hip_bf16.h>

// HamGraphConvolution: N=100k nodes, D=64 feats, H=4 heads (DK=16), E=1.6M edges.
// xt = c1*x + c2*(x@W^T)  (Hamiltonian 4-step linear recurrence folded on host)
// GAT-style attention normalized over col, aggregated over row.
// Softmax max-subtraction skipped: shift-invariant, eps 1e-16 unreachable.
// R11: xt stored bf16 (sole consumer is k_aggr's random row-gather; halves
//     the 410MB logical gather traffic; scores stay fp32 -> err ~0.02 vs
//     0.2375 threshold). Scan launches fused 4->2. R10 evidence: k_aggr
//     61us @ FETCH 183MB, HBM 43% = gather-miss bound.

#define LRELU(v) ((v) > 0.0f ? (v) : 0.2f * (v))

#define EC 4096      // edges per hist/scatter block
#define BSC 256      // col-bucket size (shift 8)
#define BSR 128      // row-bucket size (shift 7)
#define NPW 8        // nodes per wave in k_node
#define NPB 32       // nodes per block (4 waves)

__device__ __forceinline__ float bf16_to_f32(unsigned short u) {
    return __uint_as_float((unsigned int)u << 16);
}
__device__ __forceinline__ unsigned short f32_to_bf16(float f) {
    __hip_bfloat16 h = __float2bfloat16(f);  // RTN
    return *reinterpret_cast<unsigned short*>(&h);
}

__global__ __launch_bounds__(256) void k_node(const float* __restrict__ x,
                                              const float* __restrict__ W,
                                              const float* __restrict__ a,
                                              unsigned short* __restrict__ xt16,
                                              float* __restrict__ s_src,
                                              float* __restrict__ s_dst,
                                              int n, float c1, float c2) {
    __shared__ float Ws[64 * 68];   // pad 68: float4-aligned rows
    __shared__ float xs[NPB * 64];  // x-tile: 8 KB
    int t = threadIdx.x;
    for (int i = t; i < 64 * 64; i += 256)
        Ws[(i >> 6) * 68 + (i & 63)] = W[i];
    {
        size_t gbase = (size_t)blockIdx.x * NPB * 64;
        for (int i = t; i < NPB * 64; i += 256) {
            size_t g = gbase + i;
            xs[i] = (g < (size_t)n * 64) ? x[g] : 0.0f;  // coalesced
        }
    }
    __syncthreads();
    int wave = t >> 6;
    int lane = t & 63;
    float a_s = a[lane & 15];
    float a_d = a[16 + (lane & 15)];
    int nbase = blockIdx.x * NPB + wave * NPW;
    const float* xw = xs + wave * NPW * 64;

    float p[NPW];
#pragma unroll
    for (int j = 0; j < NPW; ++j) p[j] = 0.0f;

#pragma unroll 2
    for (int k4 = 0; k4 < 64; k4 += 4) {
        // per-lane W row segment (b128); x reads are wave-uniform -> broadcast
        float4 wr = *(const float4*)(Ws + lane * 68 + k4);
#pragma unroll
        for (int j = 0; j < NPW; ++j) {
            float4 xb = *(const float4*)(xw + j * 64 + k4);
            p[j] = fmaf(xb.x, wr.x, p[j]);
            p[j] = fmaf(xb.y, wr.y, p[j]);
            p[j] = fmaf(xb.z, wr.z, p[j]);
            p[j] = fmaf(xb.w, wr.w, p[j]);
        }
    }

#pragma unroll
    for (int j = 0; j < NPW; ++j) {  // constant j: p[] scalarizes
        int node = nbase + j;
        if (node < n) {
            float xv = xw[j * 64 + lane];
            float xtv = c1 * xv + c2 * p[j];
            xt16[(size_t)node * 64 + lane] = f32_to_bf16(xtv);
            float ss = xtv * a_s;  // scores stay fp32
            float sd = xtv * a_d;
#pragma unroll
            for (int off = 8; off >= 1; off >>= 1) {
                ss += __shfl_xor(ss, off, 64);
                sd += __shfl_xor(sd, off, 64);
            }
            if ((lane & 15) == 0) {
                int h = lane >> 4;
                s_src[node * 4 + h] = ss;
                s_dst[node * 4 + h] = sd;
            }
        }
    }
}

// per-block LDS histograms of row>>7 and col>>8; H layout [bucket][block]
__global__ __launch_bounds__(256) void k_hist(const int* __restrict__ row,
                                              const int* __restrict__ col,
                                              int* __restrict__ Hr,
                                              int* __restrict__ Hc,
                                              int e, int nblk, int nbr, int nbc) {
    __shared__ int hr[1024];
    __shared__ int hc[512];
    int t = threadIdx.x;
    for (int i = t; i < 1024; i += 256) hr[i] = 0;
    for (int i = t; i < 512; i += 256) hc[i] = 0;
    __syncthreads();
    int base = blockIdx.x * EC;
#pragma unroll
    for (int j = 0; j < EC / 256; ++j) {
        int i = base + t + j * 256;
        if (i < e) {
            atomicAdd(&hr[row[i] >> 7], 1);
            atomicAdd(&hc[col[i] >> 8], 1);
        }
    }
    __syncthreads();
    for (int b = t; b < nbr; b += 256) Hr[(size_t)b * nblk + blockIdx.x] = hr[b];
    for (int b = t; b < nbc; b += 256) Hc[(size_t)b * nblk + blockIdx.x] = hc[b];
}

// fused: exclusive scan of Hr rows (blocks [0,nbr)) and Hc rows (blocks
// [nbr, nbr+nbc)); per-bucket totals to BtotR/BtotC. nblk<=512.
__global__ __launch_bounds__(256) void k_scanH2(int* __restrict__ Hr,
                                                int* __restrict__ Hc,
                                                int* __restrict__ BtotR,
                                                int* __restrict__ BtotC,
                                                int nblk, int nbr) {
    __shared__ int vals[512];
    __shared__ int part[256];
    int t = threadIdx.x;
    int bb = blockIdx.x;
    int* Hb;
    int* Btot;
    if (bb < nbr) {
        Hb = Hr + (size_t)bb * nblk;
        Btot = BtotR + bb;
    } else {
        Hb = Hc + (size_t)(bb - nbr) * nblk;
        Btot = BtotC + (bb - nbr);
    }
    for (int i = t; i < nblk; i += 256) vals[i] = Hb[i];
    __syncthreads();
    int c0 = t * 2;
    int s = 0;
#pragma unroll
    for (int j = 0; j < 2; ++j)
        if (c0 + j < nblk) s += vals[c0 + j];
    part[t] = s;
    __syncthreads();
    for (int d = 1; d < 256; d <<= 1) {
        int add = (t >= d) ? part[t - d] : 0;
        __syncthreads();
        part[t] += add;
        __syncthreads();
    }
    int run = part[t] - s;
#pragma unroll
    for (int j = 0; j < 2; ++j) {
        int i = c0 + j;
        if (i < nblk) {
            int v = vals[i];
            Hb[i] = run;
            run += v;
        }
    }
    if (t == 255) *Btot = part[255];
}

// fused: block 0 scans BtotR->BbR, block 1 scans BtotC->BbC
__global__ __launch_bounds__(256) void k_base2(const int* __restrict__ BtotR,
                                               int* __restrict__ BbR, int nbr,
                                               const int* __restrict__ BtotC,
                                               int* __restrict__ BbC, int nbc) {
    const int* Btot = (blockIdx.x == 0) ? BtotR : BtotC;
    int* Bbase = (blockIdx.x == 0) ? BbR : BbC;
    int nb = (blockIdx.x == 0) ? nbr : nbc;
    __shared__ int part[256];
    __shared__ int carry;
    int t = threadIdx.x;
    if (t == 0) carry = 0;
    __syncthreads();
    for (int base = 0; base < nb; base += 256) {
        int i = base + t;
        int v = (i < nb) ? Btot[i] : 0;
        part[t] = v;
        __syncthreads();
        for (int d = 1; d < 256; d <<= 1) {
            int add = (t >= d) ? part[t - d] : 0;
            __syncthreads();
            part[t] += add;
            __syncthreads();
        }
        if (i < nb) Bbase[i] = carry + part[t] - v;
        __syncthreads();
        if (t == 0) carry += part[255];
        __syncthreads();
    }
    if (t == 0) Bbase[nb] = carry;
}

// scatter edges into c-bucketed ebc (payload r<<8|c_low) and r-bucketed ebr
// (payload c<<7|r_low) using LDS cursors; plain stores, no global atomics
__global__ __launch_bounds__(256) void k_scatter_dual(
    const int* __restrict__ row, const int* __restrict__ col,
    const int* __restrict__ Hr, const int* __restrict__ Hc,
    const int* __restrict__ BbR, const int* __restrict__ BbC,
    int* __restrict__ ebr, int* __restrict__ ebc,
    int e, int nblk, int nbr, int nbc) {
    __shared__ int curr[1024];
    __shared__ int curc[512];
    int t = threadIdx.x;
    int blk = blockIdx.x;
    for (int b = t; b < nbr; b += 256) curr[b] = BbR[b] + Hr[(size_t)b * nblk + blk];
    for (int b = t; b < nbc; b += 256) curc[b] = BbC[b] + Hc[(size_t)b * nblk + blk];
    __syncthreads();
    int base = blk * EC;
#pragma unroll
    for (int j = 0; j < EC / 256; ++j) {
        int i = base + t + j * 256;
        if (i < e) {
            int r = row[i], c = col[i];
            int pr = atomicAdd(&curr[r >> 7], 1);
            ebr[pr] = (c << 7) | (r & 127);
            int pc = atomicAdd(&curc[c >> 8], 1);
            ebc[pc] = (r << 8) | (c & 255);
        }
    }
}

// block per col-bucket: exp sums into LDS, write rden (no global atomics)
__global__ __launch_bounds__(256) void k_denom_b(const int* __restrict__ ebc,
                                                 const int* __restrict__ BbC,
                                                 const float* __restrict__ s_src,
                                                 const float* __restrict__ s_dst,
                                                 float* __restrict__ rden, int n) {
    __shared__ float acc[BSC * 4];
    __shared__ float sd[BSC * 4];
    int t = threadIdx.x;
    int b = blockIdx.x;
    int cbase = b << 8;
    for (int i = t; i < BSC * 4; i += 256) {
        acc[i] = 0.0f;
        int c4 = cbase * 4 + i;
        sd[i] = (c4 < n * 4) ? s_dst[c4] : 0.0f;
    }
    __syncthreads();
    int start = BbC[b], end = BbC[b + 1];
    for (int i = start + t; i < end; i += 256) {
        int p = ebc[i];
        int r = p >> 8, cl = p & 255;
        float4 ss = *(const float4*)(s_src + (size_t)r * 4);
        atomicAdd(&acc[cl * 4 + 0], __expf(LRELU(ss.x + sd[cl * 4 + 0])));
        atomicAdd(&acc[cl * 4 + 1], __expf(LRELU(ss.y + sd[cl * 4 + 1])));
        atomicAdd(&acc[cl * 4 + 2], __expf(LRELU(ss.z + sd[cl * 4 + 2])));
        atomicAdd(&acc[cl * 4 + 3], __expf(LRELU(ss.w + sd[cl * 4 + 3])));
    }
    __syncthreads();
    for (int i = t; i < BSC * 4; i += 256) {
        int c4 = cbase * 4 + i;
        if (c4 < n * 4) rden[c4] = 1.0f / (acc[i] + 1e-16f);
    }
}

// level-2 counting sort within row-bucket: ebr -> row-sorted (cw_c, cw_w),
// writes global rowptr; w computed here (thread-per-edge, independent loads)
__global__ __launch_bounds__(256) void k_sort2(const int* __restrict__ ebr,
                                               const int* __restrict__ BbR,
                                               const float* __restrict__ s_src,
                                               const float* __restrict__ s_dst,
                                               const float* __restrict__ rden,
                                               int* __restrict__ rowptr,
                                               int* __restrict__ cw_c,
                                               float* __restrict__ cw_w,
                                               int n, int e) {
    __shared__ int cnt[BSR];
    __shared__ int pfx[BSR];
    __shared__ int cur[BSR];
    __shared__ float ssh[BSR * 4];
    int t = threadIdx.x;
    int b = blockIdx.x;
    int rbase = b << 7;
    if (t < BSR) cnt[t] = 0;
    for (int i = t; i < BSR * 4; i += 256) {
        int g = rbase * 4 + i;
        ssh[i] = (g < n * 4) ? s_src[g] : 0.0f;
    }
    __syncthreads();
    int start = BbR[b], end = BbR[b + 1];
    for (int i = start + t; i < end; i += 256)
        atomicAdd(&cnt[ebr[i] & 127], 1);
    __syncthreads();
    if (t < BSR) pfx[t] = cnt[t];
    __syncthreads();
    for (int d = 1; d < BSR; d <<= 1) {
        int v = (t < BSR && t >= d) ? pfx[t - d] : 0;
        __syncthreads();
        if (t < BSR) pfx[t] += v;
        __syncthreads();
    }
    if (t < BSR) {
        int excl = start + pfx[t] - cnt[t];
        cur[t] = excl;
        int r = rbase + t;
        if (r < n) rowptr[r] = excl;
    }
    if (b == 0 && t == 0) rowptr[n] = e;
    __syncthreads();
    for (int i = start + t; i < end; i += 256) {
        int p = ebr[i];
        int rl = p & 127, c = p >> 7;
        float4 sd = *(const float4*)(s_dst + (size_t)c * 4);
        float4 rd = *(const float4*)(rden + (size_t)c * 4);
        float wv = __expf(LRELU(ssh[rl * 4 + 0] + sd.x)) * rd.x +
                   __expf(LRELU(ssh[rl * 4 + 1] + sd.y)) * rd.y +
                   __expf(LRELU(ssh[rl * 4 + 2] + sd.z)) * rd.z +
                   __expf(LRELU(ssh[rl * 4 + 3] + sd.w)) * rd.w;
        int pos = atomicAdd(&cur[rl], 1);
        cw_c[pos] = c;
        cw_w[pos] = 0.25f * wv;
    }
}

// wave-per-row CSR gather-reduce: register acc, 8 bf16 gathers in flight
__global__ __launch_bounds__(256) void k_aggr(const int* __restrict__ rowptr,
                                              const int* __restrict__ cw_c,
                                              const float* __restrict__ cw_w,
                                              const unsigned short* __restrict__ xt16,
                                              float* __restrict__ out, int n) {
    int r = blockIdx.x * 4 + (threadIdx.x >> 6);
    if (r >= n) return;
    int lane = threadIdx.x & 63;
    int start = rowptr[r], end = rowptr[r + 1];
    float acc = 0.0f;
    for (int base = start; base < end; base += 64) {
        int m = min(64, end - base);
        int cc = 0;
        float ww = 0.0f;
        if (lane < m) {
            cc = cw_c[base + lane];
            ww = cw_w[base + lane];
        }
        int k = 0;
        for (; k + 8 <= m; k += 8) {
            int c0 = __shfl(cc, k + 0, 64), c1 = __shfl(cc, k + 1, 64);
            int c2 = __shfl(cc, k + 2, 64), c3 = __shfl(cc, k + 3, 64);
            int c4 = __shfl(cc, k + 4, 64), c5 = __shfl(cc, k + 5, 64);
            int c6 = __shfl(cc, k + 6, 64), c7 = __shfl(cc, k + 7, 64);
            float w0 = __shfl(ww, k + 0, 64), w1 = __shfl(ww, k + 1, 64);
            float w2 = __shfl(ww, k + 2, 64), w3 = __shfl(ww, k + 3, 64);
            float w4 = __shfl(ww, k + 4, 64), w5 = __shfl(ww, k + 5, 64);
            float w6 = __shfl(ww, k + 6, 64), w7 = __shfl(ww, k + 7, 64);
            unsigned short u0 = xt16[(size_t)c0 * 64 + lane];
            unsigned short u1 = xt16[(size_t)c1 * 64 + lane];
            unsigned short u2 = xt16[(size_t)c2 * 64 + lane];
            unsigned short u3 = xt16[(size_t)c3 * 64 + lane];
            unsigned short u4 = xt16[(size_t)c4 * 64 + lane];
            unsigned short u5 = xt16[(size_t)c5 * 64 + lane];
            unsigned short u6 = xt16[(size_t)c6 * 64 + lane];
            unsigned short u7 = xt16[(size_t)c7 * 64 + lane];
            acc = fmaf(w0, bf16_to_f32(u0), acc);
            acc = fmaf(w1, bf16_to_f32(u1), acc);
            acc = fmaf(w2, bf16_to_f32(u2), acc);
            acc = fmaf(w3, bf16_to_f32(u3), acc);
            acc = fmaf(w4, bf16_to_f32(u4), acc);
            acc = fmaf(w5, bf16_to_f32(u5), acc);
            acc = fmaf(w6, bf16_to_f32(u6), acc);
            acc = fmaf(w7, bf16_to_f32(u7), acc);
        }
        for (; k < m; ++k) {
            int c0 = __shfl(cc, k, 64);
            float w0 = __shfl(ww, k, 64);
            acc = fmaf(w0, bf16_to_f32(xt16[(size_t)c0 * 64 + lane]), acc);
        }
    }
    out[(size_t)r * 64 + lane] = acc;
}

extern "C" void kernel_launch(void* const* d_in, const int* in_sizes, int n_in,
                              void* d_out, int out_size, void* d_ws, size_t ws_size,
                              hipStream_t stream) {
    const float* x = (const float*)d_in[0];
    const int* ei = (const int*)d_in[1];
    // d_in[2] = edge_weight: unused by the reference
    const float* W = (const float*)d_in[3];
    const float* a = (const float*)d_in[4];
    int n = in_sizes[0] / 64;
    int e = in_sizes[1] / 2;
    const int* row = ei;
    const int* col = ei + e;
    float* out = (float*)d_out;

    int nblk = (e + EC - 1) / EC;       // 391 (<=512 for k_scanH2)
    int nbr = (n + BSR - 1) / BSR;      // 782 (<=1024)
    int nbc = (n + BSC - 1) / BSC;      // 391 (<=512)

    size_t o = 0;
    auto take = [&](size_t cnt) {
        size_t p = o;
        o += (cnt + 3) & ~(size_t)3;
        return p;
    };
    int* wsi = (int*)d_ws;
    unsigned short* xt16 = (unsigned short*)(wsi + take((size_t)n * 32));  // n*64 bf16
    float* s_src = (float*)(wsi + take((size_t)n * 4));
    float* s_dst = (float*)(wsi + take((size_t)n * 4));
    float* rden = (float*)(wsi + take((size_t)n * 4));
    int* Hr = wsi + take((size_t)nbr * nblk);
    int* Hc = wsi + take((size_t)nbc * nblk);
    int* BtotR = wsi + take(nbr);
    int* BbR = wsi + take(nbr + 1);
    int* BtotC = wsi + take(nbc);
    int* BbC = wsi + take(nbc + 1);
    int* ebr = wsi + take(e);
    int* ebc = wsi + take(e);
    float* cw_w = (float*)(wsi + take(e));
    int* rowptr = wsi + take(n + 1);
    int* cw_c = ebc;  // alias: ebc dead after k_denom_b, k_sort2 runs after

    // Fold 4-step (q,p) <- (q+0.25p, p-0.25q): xt = aq*x + bq*(x@W^T)
    float aq = 1.f, bq = 0.f, ap = 0.f, bp = 1.f;
    for (int i = 0; i < 4; ++i) {
        float naq = aq + 0.25f * ap, nbq = bq + 0.25f * bp;
        float nap = ap - 0.25f * aq, nbp = bp - 0.25f * bq;
        aq = naq; bq = nbq; ap = nap; bp = nbp;
    }

    k_node<<<(n + NPB - 1) / NPB, 256, 0, stream>>>(x, W, a, xt16, s_src, s_dst,
                                                    n, aq, bq);
    k_hist<<<nblk, 256, 0, stream>>>(row, col, Hr, Hc, e, nblk, nbr, nbc);
    k_scanH2<<<nbr + nbc, 256, 0, stream>>>(Hr, Hc, BtotR, BtotC, nblk, nbr);
    k_base2<<<2, 256, 0, stream>>>(BtotR, BbR, nbr, BtotC, BbC, nbc);
    k_scatter_dual<<<nblk, 256, 0, stream>>>(row, col, Hr, Hc, BbR, BbC,
                                             ebr, ebc, e, nblk, nbr, nbc);
    k_denom_b<<<nbc, 256, 0, stream>>>(ebc, BbC, s_src, s_dst, rden, n);
    k_sort2<<<nbr, 256, 0, stream>>>(ebr, BbR, s_src, s_dst, rden,
                                     rowptr, cw_c, cw_w, n, e);
    k_aggr<<<(n + 3) / 4, 256, 0, stream>>>(rowptr, cw_c, cw_w, xt16, out, n);
}